// Round 3
// baseline (241.512 us; speedup 1.0000x reference)
//
#include <hip/hip_runtime.h>
#include <hip/hip_fp16.h>

#define N_NODES 50000
#define N_EDGES 800000
#define NPAD    50176          // 196*256: graph-2 node base, bucket-aligned
#define NBKT    392            // (2*NPAD)/256 buckets of 256 nodes
#define BCAP    6144           // bucket capacity; mean 4082, sigma 64 -> +32 sigma
#define PBN     16             // nodes per pull block (NPAD % PBN == 0)
#define LCAP    1024           // staged csr window cap (mean 256, +48 sigma)
#define X1S     136            // LDS X1 stride (halfs): 272 B rows, 16B-aligned
#define EPB     2048           // edges per binA block (was 4096: 1.5 blk/CU -> 3.06)
#define NEB     ((2 * N_EDGES + EPB - 1) / EPB)   // 782 edge blocks
static_assert(N_NODES < 65536, "u16 CSR requires local node ids < 65536");
// LAYOUT RULE: all intermediate buffers indexed by PADDED gid (g*NPAD + i).
// Compaction to the harness's [2*N_NODES,64] output only at pull-2's store.
// Gather/GEMM feature buffers are fp16; all accumulation fp32 (MFMA C=f32).

typedef _Float16 __attribute__((ext_vector_type(8))) half8;
typedef float    __attribute__((ext_vector_type(4))) floatx4;

// Per-block edge-index stride detection (int64 vs int32): odd 32-bit words of
// little-endian int64 with values < 2^31 are all zero.
__device__ __forceinline__ int detect_stride_block(const int* raw1, int* sflag) {
    int odd = 0;
    for (int i = threadIdx.x; i < 2048; i += 256) odd |= raw1[2 * i + 1];
    if (threadIdx.x == 0) *sflag = 0;
    __syncthreads();
    if (odd) atomicOr(sflag, 1);
    __syncthreads();
    return *sflag ? 1 : 2;
}

// ---------------------------------------------------------------------------
// Pass A, SINGLE-PASS, NEB edge-blocks x EPB edges: stage packed entry +
// bucket id in LDS while building the per-block bucket histogram; reserve
// global runs; place from LDS. Entry: (dst_in_bucket << 16) | src_local.
// R2: EPB 4096->2048. binA was 47us at 12% occupancy (1.5 blocks/CU,
// VALUBusy 2.9% -- pure exposed latency). 2x blocks = 2x resident waves.
// Blocks NEB/NEB+1 pack W1/W2 into MFMA B-fragment order.
// The LAST edge-block to finish (device-scope done-counter, non-blocking)
// computes the exclusive scan of bcount into bexcl.
// ---------------------------------------------------------------------------
__global__ __launch_bounds__(256) void binA_k(const int* __restrict__ raw1,
        const int* __restrict__ raw2, const float* __restrict__ W1,
        const float* __restrict__ W2, unsigned* __restrict__ bcount,
        unsigned* __restrict__ bbuf, _Float16* __restrict__ Wf1,
        _Float16* __restrict__ Wf2, unsigned* __restrict__ done,
        int* __restrict__ bexcl) {
    if (blockIdx.x >= NEB) {                 // fused wprep
        const int wsel = blockIdx.x - NEB;
        const float* W = wsel ? W2 : W1;
        _Float16* Wf = wsel ? Wf2 : Wf1;
        const int M = wsel ? 64 : 128;
        const int NT = M / 16;
        for (int i = threadIdx.x; i < 8192; i += 256) {   // 16 frags x 512
            int f = i >> 9, r = i & 511;
            int lane = r >> 3, j = r & 7;
            int kc = f / NT, nt = f % NT;
            int k = kc * 32 + (lane >> 4) * 8 + j;
            int m = nt * 16 + (lane & 15);
            Wf[i] = (_Float16)W[k * M + m];
        }
        return;
    }
    __shared__ unsigned ent[EPB];            // 8 KB
    __shared__ unsigned short ebkt[EPB];     // 4 KB
    __shared__ unsigned hist[NBKT], gofs[NBKT];
    __shared__ int sflag;
    const int stride = detect_stride_block(raw1, &sflag);
    const int tid = threadIdx.x;
    for (int b = tid; b < NBKT; b += 256) hist[b] = 0u;
    __syncthreads();
    const long long e0 = (long long)blockIdx.x * EPB;
    #pragma unroll 4
    for (int it = 0; it < EPB / 256; it++) {
        long long e = e0 + it * 256 + tid;
        if (e < 2LL * N_EDGES) {
            int g2 = e >= N_EDGES;
            const int* raw = g2 ? raw2 : raw1;
            long long el = e - (g2 ? N_EDGES : 0);
            int s = raw[el * stride];
            int d = raw[((long long)N_EDGES + el) * stride];
            int gid = g2 * NPAD + d;
            int bkt = gid >> 8;
            int i = it * 256 + tid;
            ent[i] = ((unsigned)(gid & 255) << 16) | (unsigned)s;
            ebkt[i] = (unsigned short)bkt;
            atomicAdd(&hist[bkt], 1u);
        }
    }
    __syncthreads();
    for (int b = tid; b < NBKT; b += 256) {
        unsigned c = hist[b];
        gofs[b] = c ? atomicAdd(&bcount[b], c) : 0u;
    }
    __syncthreads();
    for (int b = tid; b < NBKT; b += 256) hist[b] = 0u;
    __syncthreads();
    #pragma unroll 4
    for (int it = 0; it < EPB / 256; it++) {
        long long e = e0 + it * 256 + tid;
        if (e < 2LL * N_EDGES) {
            int i = it * 256 + tid;
            int bkt = (int)ebkt[i];
            unsigned r = atomicAdd(&hist[bkt], 1u);
            unsigned pos = gofs[bkt] + r;
            if (pos < BCAP) bbuf[(size_t)bkt * BCAP + pos] = ent[i];
        }
    }
    // ---- last-finisher computes exclusive bucket scan (no block ever waits) ----
    __syncthreads();
    __shared__ int lastf;
    if (tid == 0) {
        __threadfence();
        lastf = (atomicAdd(done, 1u) == (unsigned)(NEB - 1)) ? 1 : 0;
    }
    __syncthreads();
    if (lastf) {
        __shared__ int t2[512];
        int v0 = (tid < NBKT) ? (int)atomicAdd(&bcount[tid], 0u) : 0;        // coherent read
        int v1 = (tid + 256 < NBKT) ? (int)atomicAdd(&bcount[tid + 256], 0u) : 0;
        t2[tid] = v0; t2[tid + 256] = v1;
        __syncthreads();
        #pragma unroll
        for (int off = 1; off < 512; off <<= 1) {
            int a0 = (tid >= off) ? t2[tid - off] : 0;
            int a1 = (tid + 256 >= off) ? t2[tid + 256 - off] : 0;
            __syncthreads();
            t2[tid] += a0; t2[tid + 256] += a1;
            __syncthreads();
        }
        if (tid < NBKT) bexcl[tid] = t2[tid] - v0;
        if (tid + 256 < NBKT) bexcl[tid + 256] = t2[tid + 256] - v1;
    }
}

// ---------------------------------------------------------------------------
// Pass B: one block per bucket. CSR base read from bexcl; per-node degree +
// rowptr + dinv; LDS-cursor CSR scatter; fused fp16 prescale sxh = dinv * x.
// R2: 256-wide Hillis-Steele scan (16 barriers) -> wave __shfl_up scan
// (6 shuffles + 2 barriers); buildB is 1.5 blocks/CU, barrier-latency-bound.
// ---------------------------------------------------------------------------
__global__ __launch_bounds__(256) void buildB_k(const unsigned* __restrict__ bcount,
        const int* __restrict__ bexcl, const unsigned* __restrict__ bbuf,
        const float* __restrict__ x1, const float* __restrict__ x2,
        unsigned short* __restrict__ csr, int* __restrict__ rowptr,
        float* __restrict__ dinv, __half* __restrict__ sxh) {
    __shared__ unsigned ent[BCAP];
    __shared__ int deg[256], cur[256];
    __shared__ int wsum[4];
    __shared__ float sdinv[256];
    const int b = blockIdx.x, tid = threadIdx.x;
    const int cnt = min((int)bcount[b], BCAP);
    const int eb = bexcl[b];
    for (int i = tid; i < cnt; i += 256) ent[i] = bbuf[(size_t)b * BCAP + i];
    deg[tid] = 0;
    __syncthreads();
    for (int i = tid; i < cnt; i += 256) atomicAdd(&deg[ent[i] >> 16], 1);
    __syncthreads();
    const int v = deg[tid];
    const int lane = tid & 63, w = tid >> 6;
    int x = v;                                    // wave-inclusive scan
    #pragma unroll
    for (int off = 1; off < 64; off <<= 1) {
        int y = __shfl_up(x, off);
        if (lane >= off) x += y;
    }
    if (lane == 63) wsum[w] = x;
    __syncthreads();
    int wpre = 0;
    #pragma unroll
    for (int i = 0; i < 4; i++) wpre += (i < w) ? wsum[i] : 0;
    const int excl = x + wpre - v;
    cur[tid] = excl;
    const int gid = b * 256 + tid;
    float dv = rsqrtf((float)v + 1.0f);          // +1 self-loop
    rowptr[gid] = eb + excl;
    dinv[gid] = dv;
    sdinv[tid] = dv;
    if (b == NBKT - 1 && tid == 255) rowptr[2 * NPAD] = eb + excl + v;
    __syncthreads();
    for (int i = tid; i < cnt; i += 256) {
        unsigned p = ent[i];
        int pos = atomicAdd(&cur[p >> 16], 1);
        csr[eb + pos] = (unsigned short)(p & 0xFFFFu);
    }
    const int g2 = (b * 256) >= NPAD;
    const float* x0 = g2 ? x2 : x1;
    const int lbase = b * 256 - (g2 ? NPAD : 0);
    for (int i = tid; i < 256 * 16; i += 256) {
        int n = i >> 4, q = i & 15;
        int local = lbase + n;
        __half2 lo = __floats2half2_rn(0.f, 0.f), hi = lo;
        if (local < N_NODES) {
            float4 vx = *(const float4*)&x0[((size_t)local * 16 + q) * 4];
            float dn = sdinv[n];
            lo = __floats2half2_rn(vx.x * dn, vx.y * dn);
            hi = __floats2half2_rn(vx.z * dn, vx.w * dn);
        }
        uint2 u; u.x = *(unsigned*)&lo; u.y = *(unsigned*)&hi;
        *(uint2*)&sxh[(size_t)(b * 256 + n) * 64 + q * 4] = u;
    }
}

// ---------------------------------------------------------------------------
// Pull aggregation, NODE-PER-SUB: block = 16 nodes, 4 waves; each wave's 4
// sub-quads own ONE node each; lane accumulates its 8-byte slice in-register
// (no cross-lane reduce). Predicated gathers; full-64-lane self-load/store.
// ---------------------------------------------------------------------------
template<bool BIAS_RELU, bool COMPACT_OUT, bool OUT_HALF>
__global__ __launch_bounds__(256) void pull_agg_k(const __half* __restrict__ sh,
        const unsigned short* __restrict__ csr, const int* __restrict__ rowptr,
        const float* __restrict__ dinv, const float* __restrict__ bias,
        void* __restrict__ outv) {
    __shared__ unsigned short lcsr[LCAP];
    __shared__ int lrp[PBN + 1];
    __shared__ float ldv[PBN];
    const int tid = threadIdx.x;
    const int n0 = blockIdx.x * PBN;             // padded node base (no straddle)
    const int g2 = n0 >= NPAD;
    const int gbase = g2 ? NPAD : 0;
    if (tid <= PBN) lrp[tid] = rowptr[n0 + tid];
    if (tid < PBN)  ldv[tid] = dinv[n0 + tid];
    __syncthreads();
    const int wb = lrp[0];
    const int wcnt = min(lrp[PBN] - wb, LCAP);
    for (int i = tid; i < wcnt; i += 256) lcsr[i] = csr[wb + i];
    __syncthreads();
    const int wv = tid >> 6, lane = tid & 63;
    const int sub = lane >> 4, fl = lane & 15;
    const int n = wv * 4 + sub;                  // this lane's node (0..15)
    const int d = n0 + n;
    const int jfull = lrp[n + 1] - wb;
    const int jb = min(lrp[n] - wb, wcnt);
    const int je = min(jfull, wcnt);
    float4 acc = {0.f, 0.f, 0.f, 0.f};
    for (int j = jb; j < je; j += 8) {
        uint2 u[8];
        #pragma unroll
        for (int k = 0; k < 8; k++) {
            uint2 v; v.x = 0u; v.y = 0u;
            int idx = j + k;
            if (idx < je) {                      // sub-uniform guard: no request if off
                int s = (int)lcsr[idx] + gbase;
                v = *(const uint2*)&sh[(size_t)s * 64 + fl * 4];
            }
            u[k] = v;
        }
        #pragma unroll
        for (int k = 0; k < 8; k += 2) {
            __half2 pa = __hadd2(*(__half2*)&u[k].x, *(__half2*)&u[k + 1].x);
            __half2 pb = __hadd2(*(__half2*)&u[k].y, *(__half2*)&u[k + 1].y);
            float2 fa = __half22float2(pa), fb = __half22float2(pb);
            acc.x += fa.x; acc.y += fa.y; acc.z += fb.x; acc.w += fb.y;
        }
    }
    for (int j2 = je; j2 < jfull; j2++) {        // LCAP overflow: global, rare
        int s = (int)csr[wb + j2] + gbase;
        uint2 u = *(const uint2*)&sh[(size_t)s * 64 + fl * 4];
        float2 f0 = __half22float2(*(__half2*)&u.x);
        float2 f1 = __half22float2(*(__half2*)&u.y);
        acc.x += f0.x; acc.y += f0.y; acc.z += f1.x; acc.w += f1.y;
    }
    uint2 su = *(const uint2*)&sh[(size_t)d * 64 + fl * 4];
    float2 sf0 = __half22float2(*(__half2*)&su.x);
    float2 sf1 = __half22float2(*(__half2*)&su.y);
    float dv = ldv[n];
    float4 o;
    o.x = (acc.x + sf0.x) * dv;
    o.y = (acc.y + sf0.y) * dv;
    o.z = (acc.z + sf1.x) * dv;
    o.w = (acc.w + sf1.y) * dv;
    if (BIAS_RELU) {
        float4 bv = *(const float4*)&bias[fl * 4];
        o.x = fmaxf(o.x + bv.x, 0.f);
        o.y = fmaxf(o.y + bv.y, 0.f);
        o.z = fmaxf(o.z + bv.z, 0.f);
        o.w = fmaxf(o.w + bv.w, 0.f);
    }
    if (OUT_HALF) {
        __half2 lo = __floats2half2_rn(o.x, o.y);
        __half2 hi = __floats2half2_rn(o.z, o.w);
        uint2 u2; u2.x = *(unsigned*)&lo; u2.y = *(unsigned*)&hi;
        *(uint2*)&((__half*)outv)[(size_t)d * 64 + fl * 4] = u2;     // padded
    } else {
        int local = d - gbase;
        if (!COMPACT_OUT) {
            *(float4*)&((float*)outv)[(size_t)d * 64 + fl * 4] = o;
        } else if (local < N_NODES) {
            size_t orow = (size_t)(g2 ? N_NODES + local : local);
            floatx4 ov; ov.x = o.x; ov.y = o.y; ov.z = o.z; ov.w = o.w;
            __builtin_nontemporal_store(ov,
                (floatx4*)&((float*)outv)[orow * 64 + fl * 4]);
        }
    }
}

// ---------------------------------------------------------------------------
// FUSED double MFMA GEMM [R11-verified]: GH = dinv * (relu(Y@W1 + b1) @ W2),
// per 128-row block, X1 routed through LDS (stride X1S=136 halfs).
// C/D layout col=lane&15, row=(lane>>4)*4+reg. Grid 784 exact.
// ---------------------------------------------------------------------------
__global__ __launch_bounds__(256) void gemm12_k(const _Float16* __restrict__ Y,
        const _Float16* __restrict__ Wf1, const float* __restrict__ b1,
        const _Float16* __restrict__ Wf2, const float* __restrict__ dinv,
        _Float16* __restrict__ GH) {
    __shared__ _Float16 X1l[128 * X1S];      // 34.8 KB
    const int tid = threadIdx.x;
    const int wv = tid >> 6, lane = tid & 63;
    const int quad = lane >> 4, c = lane & 15;
    const int lrow0 = wv * 32;               // wave's 32 local rows
    const int grow0 = blockIdx.x * 128 + lrow0;
    // ---- phase 1: X1 = relu(Y @ W1 + b1) -> LDS ----
    {
        half8 bf[2][8];                      // K=64 (KC=2), M=128 (NT=8)
        #pragma unroll
        for (int kc = 0; kc < 2; kc++)
            #pragma unroll
            for (int nt = 0; nt < 8; nt++)
                bf[kc][nt] = *(const half8*)&Wf1[((kc * 8 + nt) * 64 + lane) * 8];
        floatx4 acc[2][8] = {};
        #pragma unroll
        for (int rt = 0; rt < 2; rt++) {
            half8 a[2];
            #pragma unroll
            for (int kc = 0; kc < 2; kc++)
                a[kc] = *(const half8*)&Y[(size_t)(grow0 + rt * 16 + c) * 64 + kc * 32 + quad * 8];
            #pragma unroll
            for (int nt = 0; nt < 8; nt++)
                #pragma unroll
                for (int kc = 0; kc < 2; kc++)
                    acc[rt][nt] = __builtin_amdgcn_mfma_f32_16x16x32_f16(
                        a[kc], bf[kc][nt], acc[rt][nt], 0, 0, 0);
        }
        float bv[8];
        #pragma unroll
        for (int nt = 0; nt < 8; nt++) bv[nt] = b1[nt * 16 + c];
        #pragma unroll
        for (int rt = 0; rt < 2; rt++)
            #pragma unroll
            for (int nt = 0; nt < 8; nt++)
                #pragma unroll
                for (int reg = 0; reg < 4; reg++) {
                    float v = fmaxf(acc[rt][nt][reg] + bv[nt], 0.f);
                    X1l[(lrow0 + rt * 16 + quad * 4 + reg) * X1S + nt * 16 + c] = (_Float16)v;
                }
    }
    __syncthreads();
    // ---- phase 2: GH = dinv * (X1 @ W2) ----
    {
        half8 bf[4][4];                      // K=128 (KC=4), M=64 (NT=4)
        #pragma unroll
        for (int kc = 0; kc < 4; kc++)
            #pragma unroll
            for (int nt = 0; nt < 4; nt++)
                bf[kc][nt] = *(const half8*)&Wf2[((kc * 4 + nt) * 64 + lane) * 8];
        floatx4 acc[2][4] = {};
        #pragma unroll
        for (int rt = 0; rt < 2; rt++) {
            half8 a[4];
            #pragma unroll
            for (int kc = 0; kc < 4; kc++)
                a[kc] = *(const half8*)&X1l[(lrow0 + rt * 16 + c) * X1S + kc * 32 + quad * 8];
            #pragma unroll
            for (int nt = 0; nt < 4; nt++)
                #pragma unroll
                for (int kc = 0; kc < 4; kc++)
                    acc[rt][nt] = __builtin_amdgcn_mfma_f32_16x16x32_f16(
                        a[kc], bf[kc][nt], acc[rt][nt], 0, 0, 0);
        }
        #pragma unroll
        for (int rt = 0; rt < 2; rt++) {
            const int rbase = grow0 + rt * 16 + quad * 4;
            float4 dvv = *(const float4*)&dinv[rbase];
            #pragma unroll
            for (int nt = 0; nt < 4; nt++)
                #pragma unroll
                for (int reg = 0; reg < 4; reg++) {
                    float v = acc[rt][nt][reg] * ((const float*)&dvv)[reg];
                    GH[(size_t)(rbase + reg) * 64 + nt * 16 + c] = (_Float16)v;
                }
        }
    }
}

extern "C" void kernel_launch(void* const* d_in, const int* in_sizes, int n_in,
                              void* d_out, int out_size, void* d_ws, size_t ws_size,
                              hipStream_t stream) {
    const float* x1 = (const float*)d_in[0];
    const int*   e1 = (const int*)d_in[1];
    const float* x2 = (const float*)d_in[2];
    const int*   e2 = (const int*)d_in[3];
    const float* W1 = (const float*)d_in[4];
    const float* b1 = (const float*)d_in[5];
    const float* W2 = (const float*)d_in[6];
    const float* b2 = (const float*)d_in[7];
    float* out = (float*)d_out;

    // Workspace (~45 MB), 256 B-aligned chunks.
    char* p = (char*)d_ws;
    auto alloc = [&](size_t bytes) { char* r = p; p += (bytes + 255) & ~(size_t)255; return r; };
    unsigned* bcount = (unsigned*)alloc((NBKT + 1) * 4);   // +1: done counter
    unsigned* done   = bcount + NBKT;
    int*      bexcl  = (int*)alloc(NBKT * 4);
    float*    dinv   = (float*)alloc((size_t)2 * NPAD * 4);
    int*      rowptr = (int*)alloc(((size_t)2 * NPAD + 1) * 4);
    unsigned* bbuf   = (unsigned*)alloc((size_t)NBKT * BCAP * 4);
    unsigned short* csr = (unsigned short*)alloc((size_t)2 * N_EDGES * 2);
    __half*   sxh    = (__half*)alloc((size_t)2 * NPAD * 64 * 2);    // fp16 feats
    _Float16* bufYh  = (_Float16*)alloc((size_t)2 * NPAD * 64 * 2);  // fp16 Y
    _Float16* Wf1    = (_Float16*)alloc(8192 * 2);
    _Float16* Wf2    = (_Float16*)alloc(8192 * 2);
    __half*   gh     = sxh;   // alias: sxh dead after pull-1; gemm12 writes gh

    // ---- CSR build + dinv + fp16 prescale + W fragment pack (fused) ----
    (void)hipMemsetAsync(bcount, 0, (NBKT + 1) * 4, stream);
    binA_k<<<NEB + 2, 256, 0, stream>>>(e1, e2, W1, W2, bcount, bbuf, Wf1, Wf2, done, bexcl);
    buildB_k<<<NBKT, 256, 0, stream>>>(bcount, bexcl, bbuf, x1, x2, csr, rowptr, dinv, sxh);

    // ---- layer 1 agg: Y = A_hat @ X (fp16) ----
    pull_agg_k<false, false, true><<<2 * NPAD / PBN, 256, 0, stream>>>(
        sxh, csr, rowptr, dinv, nullptr, bufYh);
    // ---- fused GEMMs: G' = fp16(dinv * (relu(Y@W1+b1) @ W2)) ----
    gemm12_k<<<784, 256, 0, stream>>>(bufYh, Wf1, b1, Wf2, dinv, (_Float16*)gh);
    // ---- layer 2 agg + epilogue: out = relu(dinv*(sum+self)+b2) ----
    pull_agg_k<true, true, false><<<2 * NPAD / PBN, 256, 0, stream>>>(
        gh, csr, rowptr, dinv, b2, out);
}

// Round 4
// 214.607 us; speedup vs baseline: 1.1254x; 1.1254x over previous
//
#include <hip/hip_runtime.h>
#include <hip/hip_fp16.h>

#define N_NODES 50000
#define N_EDGES 800000
#define NPAD    50176          // 196*256: graph-2 node base, bucket-aligned
#define NBKT    392            // (2*NPAD)/256 buckets of 256 nodes
#define BCAP    6144           // bucket capacity; mean 4082, sigma 64 -> +32 sigma
#define PBN     16             // nodes per pull block (NPAD % PBN == 0)
#define LCAP    1024           // staged csr window cap (mean 256, +48 sigma)
#define X1S     136            // LDS X1 stride (halfs): 272 B rows, 16B-aligned
#define EPB     4096           // edges per binA block (R3: 2048 regressed -- write
                               // amplification, not occupancy, limits binA)
#define NEB     ((2 * N_EDGES + EPB - 1) / EPB)   // 391 edge blocks
static_assert(N_NODES < 65536, "u16 CSR requires local node ids < 65536");
// LAYOUT RULE: all intermediate buffers indexed by PADDED gid (g*NPAD + i).
// Compaction to the harness's [2*N_NODES,64] output only at pull-2's store.
// Gather/GEMM feature buffers are fp16; all accumulation fp32 (MFMA C=f32).

typedef _Float16 __attribute__((ext_vector_type(8))) half8;
typedef float    __attribute__((ext_vector_type(4))) floatx4;

// Per-block edge-index stride detection (int64 vs int32): odd 32-bit words of
// little-endian int64 with values < 2^31 are all zero.
__device__ __forceinline__ int detect_stride_block(const int* raw1, int* sflag) {
    int odd = 0;
    for (int i = threadIdx.x; i < 2048; i += 256) odd |= raw1[2 * i + 1];
    if (threadIdx.x == 0) *sflag = 0;
    __syncthreads();
    if (odd) atomicOr(sflag, 1);
    __syncthreads();
    return *sflag ? 1 : 2;
}

// ---------------------------------------------------------------------------
// Pass A, SINGLE-PASS, NEB edge-blocks x EPB edges.
// R4: COALESCED FLUSH. R2/R3 profiling showed binA is bound by scattered
// 4B bbuf writes (WRITE_SIZE 2.8-4.5x payload; time tracks write
// transactions, occupancy irrelevant). Now: block-local counting sort by
// bucket in LDS (hist scan -> lofs; LDS-cursor scatter of entry indices
// into sidx), then flush in sorted order so consecutive lanes hit
// consecutive addresses of each bucket's contiguous global run (mean 42B)
// -> wave coalescer merges ~10 stores/run into 1-2 transactions.
// Entry: (dst_in_bucket << 16) | src_local. Blocks NEB/NEB+1 pack W1/W2
// into MFMA B-fragment order. Last-finishing edge block (device-scope done
// counter, non-blocking) computes the bucket-base exclusive scan -> bexcl.
// ---------------------------------------------------------------------------
__global__ __launch_bounds__(256) void binA_k(const int* __restrict__ raw1,
        const int* __restrict__ raw2, const float* __restrict__ W1,
        const float* __restrict__ W2, unsigned* __restrict__ bcount,
        unsigned* __restrict__ bbuf, _Float16* __restrict__ Wf1,
        _Float16* __restrict__ Wf2, unsigned* __restrict__ done,
        int* __restrict__ bexcl) {
    if (blockIdx.x >= NEB) {                 // fused wprep
        const int wsel = blockIdx.x - NEB;
        const float* W = wsel ? W2 : W1;
        _Float16* Wf = wsel ? Wf2 : Wf1;
        const int M = wsel ? 64 : 128;
        const int NT = M / 16;
        for (int i = threadIdx.x; i < 8192; i += 256) {   // 16 frags x 512
            int f = i >> 9, r = i & 511;
            int lane = r >> 3, j = r & 7;
            int kc = f / NT, nt = f % NT;
            int k = kc * 32 + (lane >> 4) * 8 + j;
            int m = nt * 16 + (lane & 15);
            Wf[i] = (_Float16)W[k * M + m];
        }
        return;
    }
    __shared__ unsigned ent[EPB];            // 16 KB
    __shared__ unsigned short ebkt[EPB];     // 8 KB
    __shared__ unsigned short sidx[EPB];     // 8 KB: bucket-sorted entry indices
    __shared__ unsigned hist[NBKT], gofs[NBKT];
    __shared__ int lofs[NBKT], cur[NBKT];
    __shared__ int t2[512];
    __shared__ int sflag;
    const int stride = detect_stride_block(raw1, &sflag);
    const int tid = threadIdx.x;
    for (int b = tid; b < NBKT; b += 256) hist[b] = 0u;
    __syncthreads();
    const long long e0 = (long long)blockIdx.x * EPB;
    const int scnt = (int)min((long long)EPB, 2LL * N_EDGES - e0);
    #pragma unroll 4
    for (int it = 0; it < EPB / 256; it++) {
        int i = it * 256 + tid;
        if (i < scnt) {
            long long e = e0 + i;
            int g2 = e >= N_EDGES;
            const int* raw = g2 ? raw2 : raw1;
            long long el = e - (g2 ? N_EDGES : 0);
            int s = raw[el * stride];
            int d = raw[((long long)N_EDGES + el) * stride];
            int gid = g2 * NPAD + d;
            int bkt = gid >> 8;
            ent[i] = ((unsigned)(gid & 255) << 16) | (unsigned)s;
            ebkt[i] = (unsigned short)bkt;
            atomicAdd(&hist[bkt], 1u);
        }
    }
    __syncthreads();
    // reserve global runs (atomic latency hidden under the local scan below)
    for (int b = tid; b < NBKT; b += 256) {
        unsigned c = hist[b];
        gofs[b] = c ? atomicAdd(&bcount[b], c) : 0u;
    }
    // exclusive scan of hist -> lofs (padded 512 Hillis-Steele)
    t2[tid] = (tid < NBKT) ? (int)hist[tid] : 0;
    t2[tid + 256] = (tid + 256 < NBKT) ? (int)hist[tid + 256] : 0;
    __syncthreads();
    #pragma unroll
    for (int off = 1; off < 512; off <<= 1) {
        int a0 = (tid >= off) ? t2[tid - off] : 0;
        int a1 = (tid + 256 >= off) ? t2[tid + 256 - off] : 0;
        __syncthreads();
        t2[tid] += a0; t2[tid + 256] += a1;
        __syncthreads();
    }
    if (tid < NBKT) { int l = t2[tid] - (int)hist[tid]; lofs[tid] = l; cur[tid] = l; }
    if (tid + 256 < NBKT) {
        int l = t2[tid + 256] - (int)hist[tid + 256];
        lofs[tid + 256] = l; cur[tid + 256] = l;
    }
    __syncthreads();
    // place entry indices in bucket-sorted order
    for (int i = tid; i < scnt; i += 256) {
        int bkt = (int)ebkt[i];
        int p = atomicAdd(&cur[bkt], 1);
        sidx[p] = (unsigned short)i;
    }
    __syncthreads();
    // coalesced flush: consecutive i within a bucket run -> consecutive addrs
    for (int i = tid; i < scnt; i += 256) {
        int e = (int)sidx[i];
        int bkt = (int)ebkt[e];
        unsigned pos = gofs[bkt] + (unsigned)(i - lofs[bkt]);
        if (pos < BCAP) bbuf[(size_t)bkt * BCAP + pos] = ent[e];
    }
    // ---- last-finisher computes exclusive bucket scan (no block ever waits) ----
    __syncthreads();
    __shared__ int lastf;
    if (tid == 0) {
        __threadfence();
        lastf = (atomicAdd(done, 1u) == (unsigned)(NEB - 1)) ? 1 : 0;
    }
    __syncthreads();
    if (lastf) {
        int v0 = (tid < NBKT) ? (int)atomicAdd(&bcount[tid], 0u) : 0;        // coherent read
        int v1 = (tid + 256 < NBKT) ? (int)atomicAdd(&bcount[tid + 256], 0u) : 0;
        t2[tid] = v0; t2[tid + 256] = v1;
        __syncthreads();
        #pragma unroll
        for (int off = 1; off < 512; off <<= 1) {
            int a0 = (tid >= off) ? t2[tid - off] : 0;
            int a1 = (tid + 256 >= off) ? t2[tid + 256 - off] : 0;
            __syncthreads();
            t2[tid] += a0; t2[tid + 256] += a1;
            __syncthreads();
        }
        if (tid < NBKT) bexcl[tid] = t2[tid] - v0;
        if (tid + 256 < NBKT) bexcl[tid + 256] = t2[tid + 256] - v1;
    }
}

// ---------------------------------------------------------------------------
// Pass B: one block per bucket. CSR base read from bexcl; per-node degree +
// rowptr + dinv; LDS-cursor CSR scatter; fused fp16 prescale sxh = dinv * x.
// Wave __shfl_up scan (6 shuffles + 2 barriers) instead of 16-barrier H-S.
// ---------------------------------------------------------------------------
__global__ __launch_bounds__(256) void buildB_k(const unsigned* __restrict__ bcount,
        const int* __restrict__ bexcl, const unsigned* __restrict__ bbuf,
        const float* __restrict__ x1, const float* __restrict__ x2,
        unsigned short* __restrict__ csr, int* __restrict__ rowptr,
        float* __restrict__ dinv, __half* __restrict__ sxh) {
    __shared__ unsigned ent[BCAP];
    __shared__ int deg[256], cur[256];
    __shared__ int wsum[4];
    __shared__ float sdinv[256];
    const int b = blockIdx.x, tid = threadIdx.x;
    const int cnt = min((int)bcount[b], BCAP);
    const int eb = bexcl[b];
    for (int i = tid; i < cnt; i += 256) ent[i] = bbuf[(size_t)b * BCAP + i];
    deg[tid] = 0;
    __syncthreads();
    for (int i = tid; i < cnt; i += 256) atomicAdd(&deg[ent[i] >> 16], 1);
    __syncthreads();
    const int v = deg[tid];
    const int lane = tid & 63, w = tid >> 6;
    int x = v;                                    // wave-inclusive scan
    #pragma unroll
    for (int off = 1; off < 64; off <<= 1) {
        int y = __shfl_up(x, off);
        if (lane >= off) x += y;
    }
    if (lane == 63) wsum[w] = x;
    __syncthreads();
    int wpre = 0;
    #pragma unroll
    for (int i = 0; i < 4; i++) wpre += (i < w) ? wsum[i] : 0;
    const int excl = x + wpre - v;
    cur[tid] = excl;
    const int gid = b * 256 + tid;
    float dv = rsqrtf((float)v + 1.0f);          // +1 self-loop
    rowptr[gid] = eb + excl;
    dinv[gid] = dv;
    sdinv[tid] = dv;
    if (b == NBKT - 1 && tid == 255) rowptr[2 * NPAD] = eb + excl + v;
    __syncthreads();
    for (int i = tid; i < cnt; i += 256) {
        unsigned p = ent[i];
        int pos = atomicAdd(&cur[p >> 16], 1);
        csr[eb + pos] = (unsigned short)(p & 0xFFFFu);
    }
    const int g2 = (b * 256) >= NPAD;
    const float* x0 = g2 ? x2 : x1;
    const int lbase = b * 256 - (g2 ? NPAD : 0);
    for (int i = tid; i < 256 * 16; i += 256) {
        int n = i >> 4, q = i & 15;
        int local = lbase + n;
        __half2 lo = __floats2half2_rn(0.f, 0.f), hi = lo;
        if (local < N_NODES) {
            float4 vx = *(const float4*)&x0[((size_t)local * 16 + q) * 4];
            float dn = sdinv[n];
            lo = __floats2half2_rn(vx.x * dn, vx.y * dn);
            hi = __floats2half2_rn(vx.z * dn, vx.w * dn);
        }
        uint2 u; u.x = *(unsigned*)&lo; u.y = *(unsigned*)&hi;
        *(uint2*)&sxh[(size_t)(b * 256 + n) * 64 + q * 4] = u;
    }
}

// ---------------------------------------------------------------------------
// Pull aggregation, NODE-PER-SUB: block = 16 nodes, 4 waves; each wave's 4
// sub-quads own ONE node each; lane accumulates its 8-byte slice in-register
// (no cross-lane reduce). Predicated gathers; full-64-lane self-load/store.
// ---------------------------------------------------------------------------
template<bool BIAS_RELU, bool COMPACT_OUT, bool OUT_HALF>
__global__ __launch_bounds__(256) void pull_agg_k(const __half* __restrict__ sh,
        const unsigned short* __restrict__ csr, const int* __restrict__ rowptr,
        const float* __restrict__ dinv, const float* __restrict__ bias,
        void* __restrict__ outv) {
    __shared__ unsigned short lcsr[LCAP];
    __shared__ int lrp[PBN + 1];
    __shared__ float ldv[PBN];
    const int tid = threadIdx.x;
    const int n0 = blockIdx.x * PBN;             // padded node base (no straddle)
    const int g2 = n0 >= NPAD;
    const int gbase = g2 ? NPAD : 0;
    if (tid <= PBN) lrp[tid] = rowptr[n0 + tid];
    if (tid < PBN)  ldv[tid] = dinv[n0 + tid];
    __syncthreads();
    const int wb = lrp[0];
    const int wcnt = min(lrp[PBN] - wb, LCAP);
    for (int i = tid; i < wcnt; i += 256) lcsr[i] = csr[wb + i];
    __syncthreads();
    const int wv = tid >> 6, lane = tid & 63;
    const int sub = lane >> 4, fl = lane & 15;
    const int n = wv * 4 + sub;                  // this lane's node (0..15)
    const int d = n0 + n;
    const int jfull = lrp[n + 1] - wb;
    const int jb = min(lrp[n] - wb, wcnt);
    const int je = min(jfull, wcnt);
    float4 acc = {0.f, 0.f, 0.f, 0.f};
    for (int j = jb; j < je; j += 8) {
        uint2 u[8];
        #pragma unroll
        for (int k = 0; k < 8; k++) {
            uint2 v; v.x = 0u; v.y = 0u;
            int idx = j + k;
            if (idx < je) {                      // sub-uniform guard: no request if off
                int s = (int)lcsr[idx] + gbase;
                v = *(const uint2*)&sh[(size_t)s * 64 + fl * 4];
            }
            u[k] = v;
        }
        #pragma unroll
        for (int k = 0; k < 8; k += 2) {
            __half2 pa = __hadd2(*(__half2*)&u[k].x, *(__half2*)&u[k + 1].x);
            __half2 pb = __hadd2(*(__half2*)&u[k].y, *(__half2*)&u[k + 1].y);
            float2 fa = __half22float2(pa), fb = __half22float2(pb);
            acc.x += fa.x; acc.y += fa.y; acc.z += fb.x; acc.w += fb.y;
        }
    }
    for (int j2 = je; j2 < jfull; j2++) {        // LCAP overflow: global, rare
        int s = (int)csr[wb + j2] + gbase;
        uint2 u = *(const uint2*)&sh[(size_t)s * 64 + fl * 4];
        float2 f0 = __half22float2(*(__half2*)&u.x);
        float2 f1 = __half22float2(*(__half2*)&u.y);
        acc.x += f0.x; acc.y += f0.y; acc.z += f1.x; acc.w += f1.y;
    }
    uint2 su = *(const uint2*)&sh[(size_t)d * 64 + fl * 4];
    float2 sf0 = __half22float2(*(__half2*)&su.x);
    float2 sf1 = __half22float2(*(__half2*)&su.y);
    float dv = ldv[n];
    float4 o;
    o.x = (acc.x + sf0.x) * dv;
    o.y = (acc.y + sf0.y) * dv;
    o.z = (acc.z + sf1.x) * dv;
    o.w = (acc.w + sf1.y) * dv;
    if (BIAS_RELU) {
        float4 bv = *(const float4*)&bias[fl * 4];
        o.x = fmaxf(o.x + bv.x, 0.f);
        o.y = fmaxf(o.y + bv.y, 0.f);
        o.z = fmaxf(o.z + bv.z, 0.f);
        o.w = fmaxf(o.w + bv.w, 0.f);
    }
    if (OUT_HALF) {
        __half2 lo = __floats2half2_rn(o.x, o.y);
        __half2 hi = __floats2half2_rn(o.z, o.w);
        uint2 u2; u2.x = *(unsigned*)&lo; u2.y = *(unsigned*)&hi;
        *(uint2*)&((__half*)outv)[(size_t)d * 64 + fl * 4] = u2;     // padded
    } else {
        int local = d - gbase;
        if (!COMPACT_OUT) {
            *(float4*)&((float*)outv)[(size_t)d * 64 + fl * 4] = o;
        } else if (local < N_NODES) {
            size_t orow = (size_t)(g2 ? N_NODES + local : local);
            floatx4 ov; ov.x = o.x; ov.y = o.y; ov.z = o.z; ov.w = o.w;
            __builtin_nontemporal_store(ov,
                (floatx4*)&((float*)outv)[orow * 64 + fl * 4]);
        }
    }
}

// ---------------------------------------------------------------------------
// FUSED double MFMA GEMM [R11-verified]: GH = dinv * (relu(Y@W1 + b1) @ W2),
// per 128-row block, X1 routed through LDS (stride X1S=136 halfs).
// C/D layout col=lane&15, row=(lane>>4)*4+reg. Grid 784 exact.
// ---------------------------------------------------------------------------
__global__ __launch_bounds__(256) void gemm12_k(const _Float16* __restrict__ Y,
        const _Float16* __restrict__ Wf1, const float* __restrict__ b1,
        const _Float16* __restrict__ Wf2, const float* __restrict__ dinv,
        _Float16* __restrict__ GH) {
    __shared__ _Float16 X1l[128 * X1S];      // 34.8 KB
    const int tid = threadIdx.x;
    const int wv = tid >> 6, lane = tid & 63;
    const int quad = lane >> 4, c = lane & 15;
    const int lrow0 = wv * 32;               // wave's 32 local rows
    const int grow0 = blockIdx.x * 128 + lrow0;
    // ---- phase 1: X1 = relu(Y @ W1 + b1) -> LDS ----
    {
        half8 bf[2][8];                      // K=64 (KC=2), M=128 (NT=8)
        #pragma unroll
        for (int kc = 0; kc < 2; kc++)
            #pragma unroll
            for (int nt = 0; nt < 8; nt++)
                bf[kc][nt] = *(const half8*)&Wf1[((kc * 8 + nt) * 64 + lane) * 8];
        floatx4 acc[2][8] = {};
        #pragma unroll
        for (int rt = 0; rt < 2; rt++) {
            half8 a[2];
            #pragma unroll
            for (int kc = 0; kc < 2; kc++)
                a[kc] = *(const half8*)&Y[(size_t)(grow0 + rt * 16 + c) * 64 + kc * 32 + quad * 8];
            #pragma unroll
            for (int nt = 0; nt < 8; nt++)
                #pragma unroll
                for (int kc = 0; kc < 2; kc++)
                    acc[rt][nt] = __builtin_amdgcn_mfma_f32_16x16x32_f16(
                        a[kc], bf[kc][nt], acc[rt][nt], 0, 0, 0);
        }
        float bv[8];
        #pragma unroll
        for (int nt = 0; nt < 8; nt++) bv[nt] = b1[nt * 16 + c];
        #pragma unroll
        for (int rt = 0; rt < 2; rt++)
            #pragma unroll
            for (int nt = 0; nt < 8; nt++)
                #pragma unroll
                for (int reg = 0; reg < 4; reg++) {
                    float v = fmaxf(acc[rt][nt][reg] + bv[nt], 0.f);
                    X1l[(lrow0 + rt * 16 + quad * 4 + reg) * X1S + nt * 16 + c] = (_Float16)v;
                }
    }
    __syncthreads();
    // ---- phase 2: GH = dinv * (X1 @ W2) ----
    {
        half8 bf[4][4];                      // K=128 (KC=4), M=64 (NT=4)
        #pragma unroll
        for (int kc = 0; kc < 4; kc++)
            #pragma unroll
            for (int nt = 0; nt < 4; nt++)
                bf[kc][nt] = *(const half8*)&Wf2[((kc * 4 + nt) * 64 + lane) * 8];
        floatx4 acc[2][4] = {};
        #pragma unroll
        for (int rt = 0; rt < 2; rt++) {
            half8 a[4];
            #pragma unroll
            for (int kc = 0; kc < 4; kc++)
                a[kc] = *(const half8*)&X1l[(lrow0 + rt * 16 + c) * X1S + kc * 32 + quad * 8];
            #pragma unroll
            for (int nt = 0; nt < 4; nt++)
                #pragma unroll
                for (int kc = 0; kc < 4; kc++)
                    acc[rt][nt] = __builtin_amdgcn_mfma_f32_16x16x32_f16(
                        a[kc], bf[kc][nt], acc[rt][nt], 0, 0, 0);
        }
        #pragma unroll
        for (int rt = 0; rt < 2; rt++) {
            const int rbase = grow0 + rt * 16 + quad * 4;
            float4 dvv = *(const float4*)&dinv[rbase];
            #pragma unroll
            for (int nt = 0; nt < 4; nt++)
                #pragma unroll
                for (int reg = 0; reg < 4; reg++) {
                    float v = acc[rt][nt][reg] * ((const float*)&dvv)[reg];
                    GH[(size_t)(rbase + reg) * 64 + nt * 16 + c] = (_Float16)v;
                }
        }
    }
}

extern "C" void kernel_launch(void* const* d_in, const int* in_sizes, int n_in,
                              void* d_out, int out_size, void* d_ws, size_t ws_size,
                              hipStream_t stream) {
    const float* x1 = (const float*)d_in[0];
    const int*   e1 = (const int*)d_in[1];
    const float* x2 = (const float*)d_in[2];
    const int*   e2 = (const int*)d_in[3];
    const float* W1 = (const float*)d_in[4];
    const float* b1 = (const float*)d_in[5];
    const float* W2 = (const float*)d_in[6];
    const float* b2 = (const float*)d_in[7];
    float* out = (float*)d_out;

    // Workspace (~45 MB), 256 B-aligned chunks.
    char* p = (char*)d_ws;
    auto alloc = [&](size_t bytes) { char* r = p; p += (bytes + 255) & ~(size_t)255; return r; };
    unsigned* bcount = (unsigned*)alloc((NBKT + 1) * 4);   // +1: done counter
    unsigned* done   = bcount + NBKT;
    int*      bexcl  = (int*)alloc(NBKT * 4);
    float*    dinv   = (float*)alloc((size_t)2 * NPAD * 4);
    int*      rowptr = (int*)alloc(((size_t)2 * NPAD + 1) * 4);
    unsigned* bbuf   = (unsigned*)alloc((size_t)NBKT * BCAP * 4);
    unsigned short* csr = (unsigned short*)alloc((size_t)2 * N_EDGES * 2);
    __half*   sxh    = (__half*)alloc((size_t)2 * NPAD * 64 * 2);    // fp16 feats
    _Float16* bufYh  = (_Float16*)alloc((size_t)2 * NPAD * 64 * 2);  // fp16 Y
    _Float16* Wf1    = (_Float16*)alloc(8192 * 2);
    _Float16* Wf2    = (_Float16*)alloc(8192 * 2);
    __half*   gh     = sxh;   // alias: sxh dead after pull-1; gemm12 writes gh

    // ---- CSR build + dinv + fp16 prescale + W fragment pack (fused) ----
    (void)hipMemsetAsync(bcount, 0, (NBKT + 1) * 4, stream);
    binA_k<<<NEB + 2, 256, 0, stream>>>(e1, e2, W1, W2, bcount, bbuf, Wf1, Wf2, done, bexcl);
    buildB_k<<<NBKT, 256, 0, stream>>>(bcount, bexcl, bbuf, x1, x2, csr, rowptr, dinv, sxh);

    // ---- layer 1 agg: Y = A_hat @ X (fp16) ----
    pull_agg_k<false, false, true><<<2 * NPAD / PBN, 256, 0, stream>>>(
        sxh, csr, rowptr, dinv, nullptr, bufYh);
    // ---- fused GEMMs: G' = fp16(dinv * (relu(Y@W1+b1) @ W2)) ----
    gemm12_k<<<784, 256, 0, stream>>>(bufYh, Wf1, b1, Wf2, dinv, (_Float16*)gh);
    // ---- layer 2 agg + epilogue: out = relu(dinv*(sum+self)+b2) ----
    pull_agg_k<true, true, false><<<2 * NPAD / PBN, 256, 0, stream>>>(
        gh, csr, rowptr, dinv, b2, out);
}

// Round 5
// 211.539 us; speedup vs baseline: 1.1417x; 1.0145x over previous
//
#include <hip/hip_runtime.h>
#include <hip/hip_fp16.h>

#define N_NODES 50000
#define N_EDGES 800000
#define NPAD    50176          // 196*256: graph-2 node base, bucket-aligned
#define NBKT    392            // (2*NPAD)/256 buckets of 256 nodes
#define BCAP    6144           // bucket capacity; mean 4082, sigma 64 -> +32 sigma
#define PBN     16             // nodes per pull block (NPAD % PBN == 0)
#define LCAP    1024           // staged csr window cap (mean 256, +48 sigma)
#define X1S     136            // LDS X1 stride (halfs): 272 B rows, 16B-aligned
#define EPB     4096           // edges per binA block
#define NEB     ((2 * N_EDGES + EPB - 1) / EPB)   // 391 edge blocks
#define CSTRIDE 16             // R5: one atomic counter per 64B line (kill false
                               // sharing: time tracked block count R0/R3/R4 ->
                               // line-granular device-atomic contention theory)
static_assert(N_NODES < 65536, "u16 CSR requires local node ids < 65536");
// LAYOUT RULE: all intermediate buffers indexed by PADDED gid (g*NPAD + i).
// Compaction to the harness's [2*N_NODES,64] output only at pull-2's store.
// Gather/GEMM feature buffers are fp16; all accumulation fp32 (MFMA C=f32).

typedef _Float16 __attribute__((ext_vector_type(8))) half8;
typedef float    __attribute__((ext_vector_type(4))) floatx4;

// Per-block edge-index stride detection (int64 vs int32): odd 32-bit words of
// little-endian int64 with values < 2^31 are all zero.
__device__ __forceinline__ int detect_stride_block(const int* raw1, int* sflag) {
    int odd = 0;
    for (int i = threadIdx.x; i < 2048; i += 256) odd |= raw1[2 * i + 1];
    if (threadIdx.x == 0) *sflag = 0;
    __syncthreads();
    if (odd) atomicOr(sflag, 1);
    __syncthreads();
    return *sflag ? 1 : 2;
}

// ---------------------------------------------------------------------------
// Pass A, SINGLE-PASS, NEB edge-blocks x EPB edges: LDS hist -> line-padded
// global reserve -> local scan -> local counting sort -> coalesced flush.
// Entry: (dst_in_bucket << 16) | src_local. Blocks NEB/NEB+1 pack W1/W2
// into MFMA B-fragment order. Last-finishing edge block (device-scope done
// counter on its OWN line) computes the bucket-base exclusive scan -> bexcl.
// R5: bcount padded to one counter per 64B line (CSTRIDE) -- R0/R3/R4 showed
// binA time scales with block count, i.e. with the same-line device-atomic
// chain, not with writes (R4: WRITE_SIZE halved, time -6%).
// ---------------------------------------------------------------------------
__global__ __launch_bounds__(256) void binA_k(const int* __restrict__ raw1,
        const int* __restrict__ raw2, const float* __restrict__ W1,
        const float* __restrict__ W2, unsigned* __restrict__ bcount,
        unsigned* __restrict__ bbuf, _Float16* __restrict__ Wf1,
        _Float16* __restrict__ Wf2, unsigned* __restrict__ done,
        int* __restrict__ bexcl) {
    if (blockIdx.x >= NEB) {                 // fused wprep
        const int wsel = blockIdx.x - NEB;
        const float* W = wsel ? W2 : W1;
        _Float16* Wf = wsel ? Wf2 : Wf1;
        const int M = wsel ? 64 : 128;
        const int NT = M / 16;
        for (int i = threadIdx.x; i < 8192; i += 256) {   // 16 frags x 512
            int f = i >> 9, r = i & 511;
            int lane = r >> 3, j = r & 7;
            int kc = f / NT, nt = f % NT;
            int k = kc * 32 + (lane >> 4) * 8 + j;
            int m = nt * 16 + (lane & 15);
            Wf[i] = (_Float16)W[k * M + m];
        }
        return;
    }
    __shared__ unsigned ent[EPB];            // 16 KB
    __shared__ unsigned short ebkt[EPB];     // 8 KB
    __shared__ unsigned short sidx[EPB];     // 8 KB: bucket-sorted entry indices
    __shared__ unsigned hist[NBKT], gofs[NBKT];
    __shared__ int lofs[NBKT], cur[NBKT];
    __shared__ int t2[512];
    __shared__ int sflag;
    const int stride = detect_stride_block(raw1, &sflag);
    const int tid = threadIdx.x;
    for (int b = tid; b < NBKT; b += 256) hist[b] = 0u;
    __syncthreads();
    const long long e0 = (long long)blockIdx.x * EPB;
    const int scnt = (int)min((long long)EPB, 2LL * N_EDGES - e0);
    #pragma unroll 4
    for (int it = 0; it < EPB / 256; it++) {
        int i = it * 256 + tid;
        if (i < scnt) {
            long long e = e0 + i;
            int g2 = e >= N_EDGES;
            const int* raw = g2 ? raw2 : raw1;
            long long el = e - (g2 ? N_EDGES : 0);
            int s = raw[el * stride];
            int d = raw[((long long)N_EDGES + el) * stride];
            int gid = g2 * NPAD + d;
            int bkt = gid >> 8;
            ent[i] = ((unsigned)(gid & 255) << 16) | (unsigned)s;
            ebkt[i] = (unsigned short)bkt;
            atomicAdd(&hist[bkt], 1u);
        }
    }
    __syncthreads();
    // reserve global runs (one counter per cache line: no false sharing)
    for (int b = tid; b < NBKT; b += 256) {
        unsigned c = hist[b];
        gofs[b] = c ? atomicAdd(&bcount[b * CSTRIDE], c) : 0u;
    }
    // exclusive scan of hist -> lofs (padded 512 Hillis-Steele)
    t2[tid] = (tid < NBKT) ? (int)hist[tid] : 0;
    t2[tid + 256] = (tid + 256 < NBKT) ? (int)hist[tid + 256] : 0;
    __syncthreads();
    #pragma unroll
    for (int off = 1; off < 512; off <<= 1) {
        int a0 = (tid >= off) ? t2[tid - off] : 0;
        int a1 = (tid + 256 >= off) ? t2[tid + 256 - off] : 0;
        __syncthreads();
        t2[tid] += a0; t2[tid + 256] += a1;
        __syncthreads();
    }
    if (tid < NBKT) { int l = t2[tid] - (int)hist[tid]; lofs[tid] = l; cur[tid] = l; }
    if (tid + 256 < NBKT) {
        int l = t2[tid + 256] - (int)hist[tid + 256];
        lofs[tid + 256] = l; cur[tid + 256] = l;
    }
    __syncthreads();
    // place entry indices in bucket-sorted order
    for (int i = tid; i < scnt; i += 256) {
        int bkt = (int)ebkt[i];
        int p = atomicAdd(&cur[bkt], 1);
        sidx[p] = (unsigned short)i;
    }
    __syncthreads();
    // coalesced flush: consecutive i within a bucket run -> consecutive addrs
    for (int i = tid; i < scnt; i += 256) {
        int e = (int)sidx[i];
        int bkt = (int)ebkt[e];
        unsigned pos = gofs[bkt] + (unsigned)(i - lofs[bkt]);
        if (pos < BCAP) bbuf[(size_t)bkt * BCAP + pos] = ent[e];
    }
    // ---- last-finisher computes exclusive bucket scan (no block ever waits) ----
    __syncthreads();
    __shared__ int lastf;
    if (tid == 0) {
        __threadfence();
        lastf = (atomicAdd(done, 1u) == (unsigned)(NEB - 1)) ? 1 : 0;
    }
    __syncthreads();
    if (lastf) {
        int v0 = (tid < NBKT) ? (int)atomicAdd(&bcount[tid * CSTRIDE], 0u) : 0;
        int v1 = (tid + 256 < NBKT) ? (int)atomicAdd(&bcount[(tid + 256) * CSTRIDE], 0u) : 0;
        t2[tid] = v0; t2[tid + 256] = v1;
        __syncthreads();
        #pragma unroll
        for (int off = 1; off < 512; off <<= 1) {
            int a0 = (tid >= off) ? t2[tid - off] : 0;
            int a1 = (tid + 256 >= off) ? t2[tid + 256 - off] : 0;
            __syncthreads();
            t2[tid] += a0; t2[tid + 256] += a1;
            __syncthreads();
        }
        if (tid < NBKT) bexcl[tid] = t2[tid] - v0;
        if (tid + 256 < NBKT) bexcl[tid + 256] = t2[tid + 256] - v1;
    }
}

// ---------------------------------------------------------------------------
// Pass B: one block per bucket. CSR base read from bexcl; per-node degree +
// rowptr + dinv; LDS-cursor CSR scatter; fused fp16 prescale sxh = dinv * x.
// Wave __shfl_up scan (6 shuffles + 2 barriers) instead of 16-barrier H-S.
// ---------------------------------------------------------------------------
__global__ __launch_bounds__(256) void buildB_k(const unsigned* __restrict__ bcount,
        const int* __restrict__ bexcl, const unsigned* __restrict__ bbuf,
        const float* __restrict__ x1, const float* __restrict__ x2,
        unsigned short* __restrict__ csr, int* __restrict__ rowptr,
        float* __restrict__ dinv, __half* __restrict__ sxh) {
    __shared__ unsigned ent[BCAP];
    __shared__ int deg[256], cur[256];
    __shared__ int wsum[4];
    __shared__ float sdinv[256];
    const int b = blockIdx.x, tid = threadIdx.x;
    const int cnt = min((int)bcount[b * CSTRIDE], BCAP);
    const int eb = bexcl[b];
    for (int i = tid; i < cnt; i += 256) ent[i] = bbuf[(size_t)b * BCAP + i];
    deg[tid] = 0;
    __syncthreads();
    for (int i = tid; i < cnt; i += 256) atomicAdd(&deg[ent[i] >> 16], 1);
    __syncthreads();
    const int v = deg[tid];
    const int lane = tid & 63, w = tid >> 6;
    int x = v;                                    // wave-inclusive scan
    #pragma unroll
    for (int off = 1; off < 64; off <<= 1) {
        int y = __shfl_up(x, off);
        if (lane >= off) x += y;
    }
    if (lane == 63) wsum[w] = x;
    __syncthreads();
    int wpre = 0;
    #pragma unroll
    for (int i = 0; i < 4; i++) wpre += (i < w) ? wsum[i] : 0;
    const int excl = x + wpre - v;
    cur[tid] = excl;
    const int gid = b * 256 + tid;
    float dv = rsqrtf((float)v + 1.0f);          // +1 self-loop
    rowptr[gid] = eb + excl;
    dinv[gid] = dv;
    sdinv[tid] = dv;
    if (b == NBKT - 1 && tid == 255) rowptr[2 * NPAD] = eb + excl + v;
    __syncthreads();
    for (int i = tid; i < cnt; i += 256) {
        unsigned p = ent[i];
        int pos = atomicAdd(&cur[p >> 16], 1);
        csr[eb + pos] = (unsigned short)(p & 0xFFFFu);
    }
    const int g2 = (b * 256) >= NPAD;
    const float* x0 = g2 ? x2 : x1;
    const int lbase = b * 256 - (g2 ? NPAD : 0);
    for (int i = tid; i < 256 * 16; i += 256) {
        int n = i >> 4, q = i & 15;
        int local = lbase + n;
        __half2 lo = __floats2half2_rn(0.f, 0.f), hi = lo;
        if (local < N_NODES) {
            float4 vx = *(const float4*)&x0[((size_t)local * 16 + q) * 4];
            float dn = sdinv[n];
            lo = __floats2half2_rn(vx.x * dn, vx.y * dn);
            hi = __floats2half2_rn(vx.z * dn, vx.w * dn);
        }
        uint2 u; u.x = *(unsigned*)&lo; u.y = *(unsigned*)&hi;
        *(uint2*)&sxh[(size_t)(b * 256 + n) * 64 + q * 4] = u;
    }
}

// ---------------------------------------------------------------------------
// Pull aggregation, NODE-PER-SUB: block = 16 nodes, 4 waves; each wave's 4
// sub-quads own ONE node each; lane accumulates its 8-byte slice in-register
// (no cross-lane reduce). Predicated gathers; full-64-lane self-load/store.
// ---------------------------------------------------------------------------
template<bool BIAS_RELU, bool COMPACT_OUT, bool OUT_HALF>
__global__ __launch_bounds__(256) void pull_agg_k(const __half* __restrict__ sh,
        const unsigned short* __restrict__ csr, const int* __restrict__ rowptr,
        const float* __restrict__ dinv, const float* __restrict__ bias,
        void* __restrict__ outv) {
    __shared__ unsigned short lcsr[LCAP];
    __shared__ int lrp[PBN + 1];
    __shared__ float ldv[PBN];
    const int tid = threadIdx.x;
    const int n0 = blockIdx.x * PBN;             // padded node base (no straddle)
    const int g2 = n0 >= NPAD;
    const int gbase = g2 ? NPAD : 0;
    if (tid <= PBN) lrp[tid] = rowptr[n0 + tid];
    if (tid < PBN)  ldv[tid] = dinv[n0 + tid];
    __syncthreads();
    const int wb = lrp[0];
    const int wcnt = min(lrp[PBN] - wb, LCAP);
    for (int i = tid; i < wcnt; i += 256) lcsr[i] = csr[wb + i];
    __syncthreads();
    const int wv = tid >> 6, lane = tid & 63;
    const int sub = lane >> 4, fl = lane & 15;
    const int n = wv * 4 + sub;                  // this lane's node (0..15)
    const int d = n0 + n;
    const int jfull = lrp[n + 1] - wb;
    const int jb = min(lrp[n] - wb, wcnt);
    const int je = min(jfull, wcnt);
    float4 acc = {0.f, 0.f, 0.f, 0.f};
    for (int j = jb; j < je; j += 8) {
        uint2 u[8];
        #pragma unroll
        for (int k = 0; k < 8; k++) {
            uint2 v; v.x = 0u; v.y = 0u;
            int idx = j + k;
            if (idx < je) {                      // sub-uniform guard: no request if off
                int s = (int)lcsr[idx] + gbase;
                v = *(const uint2*)&sh[(size_t)s * 64 + fl * 4];
            }
            u[k] = v;
        }
        #pragma unroll
        for (int k = 0; k < 8; k += 2) {
            __half2 pa = __hadd2(*(__half2*)&u[k].x, *(__half2*)&u[k + 1].x);
            __half2 pb = __hadd2(*(__half2*)&u[k].y, *(__half2*)&u[k + 1].y);
            float2 fa = __half22float2(pa), fb = __half22float2(pb);
            acc.x += fa.x; acc.y += fa.y; acc.z += fb.x; acc.w += fb.y;
        }
    }
    for (int j2 = je; j2 < jfull; j2++) {        // LCAP overflow: global, rare
        int s = (int)csr[wb + j2] + gbase;
        uint2 u = *(const uint2*)&sh[(size_t)s * 64 + fl * 4];
        float2 f0 = __half22float2(*(__half2*)&u.x);
        float2 f1 = __half22float2(*(__half2*)&u.y);
        acc.x += f0.x; acc.y += f0.y; acc.z += f1.x; acc.w += f1.y;
    }
    uint2 su = *(const uint2*)&sh[(size_t)d * 64 + fl * 4];
    float2 sf0 = __half22float2(*(__half2*)&su.x);
    float2 sf1 = __half22float2(*(__half2*)&su.y);
    float dv = ldv[n];
    float4 o;
    o.x = (acc.x + sf0.x) * dv;
    o.y = (acc.y + sf0.y) * dv;
    o.z = (acc.z + sf1.x) * dv;
    o.w = (acc.w + sf1.y) * dv;
    if (BIAS_RELU) {
        float4 bv = *(const float4*)&bias[fl * 4];
        o.x = fmaxf(o.x + bv.x, 0.f);
        o.y = fmaxf(o.y + bv.y, 0.f);
        o.z = fmaxf(o.z + bv.z, 0.f);
        o.w = fmaxf(o.w + bv.w, 0.f);
    }
    if (OUT_HALF) {
        __half2 lo = __floats2half2_rn(o.x, o.y);
        __half2 hi = __floats2half2_rn(o.z, o.w);
        uint2 u2; u2.x = *(unsigned*)&lo; u2.y = *(unsigned*)&hi;
        *(uint2*)&((__half*)outv)[(size_t)d * 64 + fl * 4] = u2;     // padded
    } else {
        int local = d - gbase;
        if (!COMPACT_OUT) {
            *(float4*)&((float*)outv)[(size_t)d * 64 + fl * 4] = o;
        } else if (local < N_NODES) {
            size_t orow = (size_t)(g2 ? N_NODES + local : local);
            floatx4 ov; ov.x = o.x; ov.y = o.y; ov.z = o.z; ov.w = o.w;
            __builtin_nontemporal_store(ov,
                (floatx4*)&((float*)outv)[orow * 64 + fl * 4]);
        }
    }
}

// ---------------------------------------------------------------------------
// FUSED double MFMA GEMM [R11-verified]: GH = dinv * (relu(Y@W1 + b1) @ W2),
// per 128-row block, X1 routed through LDS (stride X1S=136 halfs).
// C/D layout col=lane&15, row=(lane>>4)*4+reg. Grid 784 exact.
// ---------------------------------------------------------------------------
__global__ __launch_bounds__(256) void gemm12_k(const _Float16* __restrict__ Y,
        const _Float16* __restrict__ Wf1, const float* __restrict__ b1,
        const _Float16* __restrict__ Wf2, const float* __restrict__ dinv,
        _Float16* __restrict__ GH) {
    __shared__ _Float16 X1l[128 * X1S];      // 34.8 KB
    const int tid = threadIdx.x;
    const int wv = tid >> 6, lane = tid & 63;
    const int quad = lane >> 4, c = lane & 15;
    const int lrow0 = wv * 32;               // wave's 32 local rows
    const int grow0 = blockIdx.x * 128 + lrow0;
    // ---- phase 1: X1 = relu(Y @ W1 + b1) -> LDS ----
    {
        half8 bf[2][8];                      // K=64 (KC=2), M=128 (NT=8)
        #pragma unroll
        for (int kc = 0; kc < 2; kc++)
            #pragma unroll
            for (int nt = 0; nt < 8; nt++)
                bf[kc][nt] = *(const half8*)&Wf1[((kc * 8 + nt) * 64 + lane) * 8];
        floatx4 acc[2][8] = {};
        #pragma unroll
        for (int rt = 0; rt < 2; rt++) {
            half8 a[2];
            #pragma unroll
            for (int kc = 0; kc < 2; kc++)
                a[kc] = *(const half8*)&Y[(size_t)(grow0 + rt * 16 + c) * 64 + kc * 32 + quad * 8];
            #pragma unroll
            for (int nt = 0; nt < 8; nt++)
                #pragma unroll
                for (int kc = 0; kc < 2; kc++)
                    acc[rt][nt] = __builtin_amdgcn_mfma_f32_16x16x32_f16(
                        a[kc], bf[kc][nt], acc[rt][nt], 0, 0, 0);
        }
        float bv[8];
        #pragma unroll
        for (int nt = 0; nt < 8; nt++) bv[nt] = b1[nt * 16 + c];
        #pragma unroll
        for (int rt = 0; rt < 2; rt++)
            #pragma unroll
            for (int nt = 0; nt < 8; nt++)
                #pragma unroll
                for (int reg = 0; reg < 4; reg++) {
                    float v = fmaxf(acc[rt][nt][reg] + bv[nt], 0.f);
                    X1l[(lrow0 + rt * 16 + quad * 4 + reg) * X1S + nt * 16 + c] = (_Float16)v;
                }
    }
    __syncthreads();
    // ---- phase 2: GH = dinv * (X1 @ W2) ----
    {
        half8 bf[4][4];                      // K=128 (KC=4), M=64 (NT=4)
        #pragma unroll
        for (int kc = 0; kc < 4; kc++)
            #pragma unroll
            for (int nt = 0; nt < 4; nt++)
                bf[kc][nt] = *(const half8*)&Wf2[((kc * 4 + nt) * 64 + lane) * 8];
        floatx4 acc[2][4] = {};
        #pragma unroll
        for (int rt = 0; rt < 2; rt++) {
            half8 a[4];
            #pragma unroll
            for (int kc = 0; kc < 4; kc++)
                a[kc] = *(const half8*)&X1l[(lrow0 + rt * 16 + c) * X1S + kc * 32 + quad * 8];
            #pragma unroll
            for (int nt = 0; nt < 4; nt++)
                #pragma unroll
                for (int kc = 0; kc < 4; kc++)
                    acc[rt][nt] = __builtin_amdgcn_mfma_f32_16x16x32_f16(
                        a[kc], bf[kc][nt], acc[rt][nt], 0, 0, 0);
        }
        #pragma unroll
        for (int rt = 0; rt < 2; rt++) {
            const int rbase = grow0 + rt * 16 + quad * 4;
            float4 dvv = *(const float4*)&dinv[rbase];
            #pragma unroll
            for (int nt = 0; nt < 4; nt++)
                #pragma unroll
                for (int reg = 0; reg < 4; reg++) {
                    float v = acc[rt][nt][reg] * ((const float*)&dvv)[reg];
                    GH[(size_t)(rbase + reg) * 64 + nt * 16 + c] = (_Float16)v;
                }
        }
    }
}

extern "C" void kernel_launch(void* const* d_in, const int* in_sizes, int n_in,
                              void* d_out, int out_size, void* d_ws, size_t ws_size,
                              hipStream_t stream) {
    const float* x1 = (const float*)d_in[0];
    const int*   e1 = (const int*)d_in[1];
    const float* x2 = (const float*)d_in[2];
    const int*   e2 = (const int*)d_in[3];
    const float* W1 = (const float*)d_in[4];
    const float* b1 = (const float*)d_in[5];
    const float* W2 = (const float*)d_in[6];
    const float* b2 = (const float*)d_in[7];
    float* out = (float*)d_out;

    // Workspace (~45 MB), 256 B-aligned chunks.
    char* p = (char*)d_ws;
    auto alloc = [&](size_t bytes) { char* r = p; p += (bytes + 255) & ~(size_t)255; return r; };
    unsigned* bcount = (unsigned*)alloc((size_t)(NBKT * CSTRIDE + CSTRIDE) * 4);
    unsigned* done   = bcount + NBKT * CSTRIDE;    // own cache line
    int*      bexcl  = (int*)alloc(NBKT * 4);
    float*    dinv   = (float*)alloc((size_t)2 * NPAD * 4);
    int*      rowptr = (int*)alloc(((size_t)2 * NPAD + 1) * 4);
    unsigned* bbuf   = (unsigned*)alloc((size_t)NBKT * BCAP * 4);
    unsigned short* csr = (unsigned short*)alloc((size_t)2 * N_EDGES * 2);
    __half*   sxh    = (__half*)alloc((size_t)2 * NPAD * 64 * 2);    // fp16 feats
    _Float16* bufYh  = (_Float16*)alloc((size_t)2 * NPAD * 64 * 2);  // fp16 Y
    _Float16* Wf1    = (_Float16*)alloc(8192 * 2);
    _Float16* Wf2    = (_Float16*)alloc(8192 * 2);
    __half*   gh     = sxh;   // alias: sxh dead after pull-1; gemm12 writes gh

    // ---- CSR build + dinv + fp16 prescale + W fragment pack (fused) ----
    (void)hipMemsetAsync(bcount, 0, (size_t)(NBKT * CSTRIDE + CSTRIDE) * 4, stream);
    binA_k<<<NEB + 2, 256, 0, stream>>>(e1, e2, W1, W2, bcount, bbuf, Wf1, Wf2, done, bexcl);
    buildB_k<<<NBKT, 256, 0, stream>>>(bcount, bexcl, bbuf, x1, x2, csr, rowptr, dinv, sxh);

    // ---- layer 1 agg: Y = A_hat @ X (fp16) ----
    pull_agg_k<false, false, true><<<2 * NPAD / PBN, 256, 0, stream>>>(
        sxh, csr, rowptr, dinv, nullptr, bufYh);
    // ---- fused GEMMs: G' = fp16(dinv * (relu(Y@W1+b1) @ W2)) ----
    gemm12_k<<<784, 256, 0, stream>>>(bufYh, Wf1, b1, Wf2, dinv, (_Float16*)gh);
    // ---- layer 2 agg + epilogue: out = relu(dinv*(sum+self)+b2) ----
    pull_agg_k<true, true, false><<<2 * NPAD / PBN, 256, 0, stream>>>(
        gh, csr, rowptr, dinv, b2, out);
}